// Round 1
// baseline (121.420 us; speedup 1.0000x reference)
//
#include <hip/hip_runtime.h>

#define CS 384
#define CH 32
#define CZ 128
#define LL 512
#define EPSV 1e-5f

// ---------------- Kernel 1: LayerNorm + two projections ----------------
// One block per sequence position l. Computes sn = LN(s[l])*gamma+beta in LDS,
// then a[l,h] = sn . w1[:,h] + b1[h] and b[l,h] = sn . w2[:,h] + b2[h].
__global__ __launch_bounds__(256) void ln_proj_kernel(
    const float* __restrict__ s, const float* __restrict__ gamma,
    const float* __restrict__ beta,
    const float* __restrict__ w1, const float* __restrict__ b1,
    const float* __restrict__ w2, const float* __restrict__ b2,
    float* __restrict__ A, float* __restrict__ B) {
  int l = blockIdx.x;
  int tid = threadIdx.x;
  __shared__ float sn[CS];
  __shared__ float red[256];
  const float* srow = s + l * CS;

  float lsum = 0.f;
  for (int c = tid; c < CS; c += 256) { float x = srow[c]; sn[c] = x; lsum += x; }
  red[tid] = lsum; __syncthreads();
  for (int off = 128; off > 0; off >>= 1) {
    if (tid < off) red[tid] += red[tid + off];
    __syncthreads();
  }
  float mu = red[0] * (1.0f / CS);
  __syncthreads();

  float lvar = 0.f;
  for (int c = tid; c < CS; c += 256) { float d = sn[c] - mu; lvar += d * d; }
  red[tid] = lvar; __syncthreads();
  for (int off = 128; off > 0; off >>= 1) {
    if (tid < off) red[tid] += red[tid + off];
    __syncthreads();
  }
  float rstd = rsqrtf(red[0] * (1.0f / CS) + EPSV);
  __syncthreads();

  for (int c = tid; c < CS; c += 256)
    sn[c] = (sn[c] - mu) * rstd * gamma[c] + beta[c];
  __syncthreads();

  // 64 outputs (32 for A, 32 for B), 4 threads each, K=384 split into 4x96.
  int o = tid >> 2, q = tid & 3;
  int h = o & 31;
  const float* w = (o < CH) ? w1 : w2;
  float acc = 0.f;
  int c0 = q * 96;
  #pragma unroll 8
  for (int c = c0; c < c0 + 96; ++c) acc += sn[c] * w[c * CH + h];
  red[tid] = acc; __syncthreads();
  if (q == 0) {
    float r = red[tid] + red[tid + 1] + red[tid + 2] + red[tid + 3];
    if (o < CH) A[l * CH + h] = r + b1[h];
    else        B[l * CH + h] = r + b2[h];
  }
}

// ---------------- Kernel 2: T[j,a,z] = sum_b B[j,b] * W[a,b,z] ----------------
// One block per j; 256 threads = (a-half, z). W reads coalesced across z.
__global__ __launch_bounds__(256) void tmat_kernel(
    const float* __restrict__ Bm, const float* __restrict__ w_out,
    float* __restrict__ T) {
  int j = blockIdx.x;
  int tid = threadIdx.x;
  int z = tid & (CZ - 1);
  int ah = tid >> 7;  // 0 or 1 -> a in [ah*16, ah*16+16)
  __shared__ float bb[CH];
  if (tid < CH) bb[tid] = Bm[j * CH + tid];
  __syncthreads();
  for (int a = ah * 16; a < ah * 16 + 16; ++a) {
    float acc = 0.f;
    #pragma unroll
    for (int b = 0; b < CH; ++b) acc += bb[b] * w_out[(a * CH + b) * CZ + z];
    T[(j * CH + a) * CZ + z] = acc;
  }
}

// ---------------- Kernel 3: z[i,j,:] = A[i,:] @ T[j,:,:] + b_out ----------------
// Grid: (8 i-tiles of 64, 512 j). Block 256 threads as 16(tx: z) x 16(ty: i).
// Each thread computes a 4i x 8z micro-tile (z = tx*4..tx*4+3 and 64+tx*4..).
__global__ __launch_bounds__(256) void outer_kernel(
    const float* __restrict__ A, const float* __restrict__ T,
    const float* __restrict__ b_out, float* __restrict__ out) {
  int it = blockIdx.x;  // 0..7
  int j  = blockIdx.y;  // 0..511
  int tid = threadIdx.x;
  __shared__ float At[CH * 64];   // [a][il]  (transposed A tile)
  __shared__ float Tl[CH * CZ];   // [a][z]
  __shared__ float bo[CZ];

  if (tid < CZ) bo[tid] = b_out[tid];

  // Stage A tile (64 x 32) transposed into LDS.
  for (int idx = tid; idx < 64 * CH; idx += 256) {
    int il = idx >> 5, a = idx & 31;
    At[a * 64 + il] = A[(it * 64 + il) * CH + a];
  }
  // Stage T_j (32 x 128) linearly via float4.
  const float4* Tg = (const float4*)(T + (size_t)j * CH * CZ);
  float4* Tl4 = (float4*)Tl;
  for (int v = tid; v < CH * CZ / 4; v += 256) Tl4[v] = Tg[v];
  __syncthreads();

  int tx = tid & 15, ty = tid >> 4;
  float acc[4][8];
  #pragma unroll
  for (int r = 0; r < 4; ++r)
    #pragma unroll
    for (int c = 0; c < 8; ++c) acc[r][c] = 0.f;

  #pragma unroll 8
  for (int a = 0; a < CH; ++a) {
    float4 av = *(const float4*)&At[a * 64 + ty * 4];
    float4 t0 = *(const float4*)&Tl[a * CZ + tx * 4];
    float4 t1 = *(const float4*)&Tl[a * CZ + 64 + tx * 4];
    const float avr[4] = {av.x, av.y, av.z, av.w};
    const float t0r[4] = {t0.x, t0.y, t0.z, t0.w};
    const float t1r[4] = {t1.x, t1.y, t1.z, t1.w};
    #pragma unroll
    for (int r = 0; r < 4; ++r) {
      #pragma unroll
      for (int c = 0; c < 4; ++c) {
        acc[r][c]     += avr[r] * t0r[c];
        acc[r][c + 4] += avr[r] * t1r[c];
      }
    }
  }

  float4 bv0 = *(const float4*)&bo[tx * 4];
  float4 bv1 = *(const float4*)&bo[64 + tx * 4];
  const float b0r[4] = {bv0.x, bv0.y, bv0.z, bv0.w};
  const float b1r[4] = {bv1.x, bv1.y, bv1.z, bv1.w};

  #pragma unroll
  for (int r = 0; r < 4; ++r) {
    int i = it * 64 + ty * 4 + r;
    float* op = out + ((size_t)i * LL + j) * CZ;
    float4 o0, o1;
    o0.x = acc[r][0] + b0r[0]; o0.y = acc[r][1] + b0r[1];
    o0.z = acc[r][2] + b0r[2]; o0.w = acc[r][3] + b0r[3];
    o1.x = acc[r][4] + b1r[0]; o1.y = acc[r][5] + b1r[1];
    o1.z = acc[r][6] + b1r[2]; o1.w = acc[r][7] + b1r[3];
    *(float4*)(op + tx * 4) = o0;
    *(float4*)(op + 64 + tx * 4) = o1;
  }
}

extern "C" void kernel_launch(void* const* d_in, const int* in_sizes, int n_in,
                              void* d_out, int out_size, void* d_ws, size_t ws_size,
                              hipStream_t stream) {
  const float* s     = (const float*)d_in[0];
  const float* gam   = (const float*)d_in[1];
  const float* bet   = (const float*)d_in[2];
  const float* w1    = (const float*)d_in[3];
  const float* b1    = (const float*)d_in[4];
  const float* w2    = (const float*)d_in[5];
  const float* b2    = (const float*)d_in[6];
  const float* w_out = (const float*)d_in[7];
  const float* b_out = (const float*)d_in[8];
  float* out = (float*)d_out;

  float* wsA = (float*)d_ws;            // 512*32 floats
  float* wsB = wsA + LL * CH;           // 512*32 floats
  float* wsT = wsB + LL * CH;           // 512*32*128 floats (8 MB)

  ln_proj_kernel<<<LL, 256, 0, stream>>>(s, gam, bet, w1, b1, w2, b2, wsA, wsB);
  tmat_kernel<<<LL, 256, 0, stream>>>(wsB, w_out, wsT);
  outer_kernel<<<dim3(8, LL), 256, 0, stream>>>(wsA, wsT, b_out, out);
}

// Round 2
// 69.991 us; speedup vs baseline: 1.7348x; 1.7348x over previous
//
#include <hip/hip_runtime.h>

#define CS 384
#define CH 32
#define CZ 128
#define LL 512
#define EPSV 1e-5f

// ---------------- Kernel 1: LayerNorm + two projections ----------------
__global__ __launch_bounds__(256) void ln_proj_kernel(
    const float* __restrict__ s, const float* __restrict__ gamma,
    const float* __restrict__ beta,
    const float* __restrict__ w1, const float* __restrict__ b1,
    const float* __restrict__ w2, const float* __restrict__ b2,
    float* __restrict__ A, float* __restrict__ B) {
  int l = blockIdx.x;
  int tid = threadIdx.x;
  __shared__ float sn[CS];
  __shared__ float red[256];
  const float* srow = s + l * CS;

  float lsum = 0.f;
  for (int c = tid; c < CS; c += 256) { float x = srow[c]; sn[c] = x; lsum += x; }
  red[tid] = lsum; __syncthreads();
  for (int off = 128; off > 0; off >>= 1) {
    if (tid < off) red[tid] += red[tid + off];
    __syncthreads();
  }
  float mu = red[0] * (1.0f / CS);
  __syncthreads();

  float lvar = 0.f;
  for (int c = tid; c < CS; c += 256) { float d = sn[c] - mu; lvar += d * d; }
  red[tid] = lvar; __syncthreads();
  for (int off = 128; off > 0; off >>= 1) {
    if (tid < off) red[tid] += red[tid + off];
    __syncthreads();
  }
  float rstd = rsqrtf(red[0] * (1.0f / CS) + EPSV);
  __syncthreads();

  for (int c = tid; c < CS; c += 256)
    sn[c] = (sn[c] - mu) * rstd * gamma[c] + beta[c];
  __syncthreads();

  // 64 outputs (32 for A, 32 for B), 4 threads each, K=384 split into 4x96.
  int o = tid >> 2, q = tid & 3;
  int h = o & 31;
  const float* w = (o < CH) ? w1 : w2;
  float acc = 0.f;
  int c0 = q * 96;
  #pragma unroll 8
  for (int c = c0; c < c0 + 96; ++c) acc += sn[c] * w[c * CH + h];
  red[tid] = acc; __syncthreads();
  if (q == 0) {
    float r = red[tid] + red[tid + 1] + red[tid + 2] + red[tid + 3];
    if (o < CH) A[l * CH + h] = r + b1[h];
    else        B[l * CH + h] = r + b2[h];
  }
}

// ---------------- Kernel 2: T[j,a,z] = sum_b B[j,b] * W[a,b,z] ----------------
// Grid (32 a, 16 j-tiles of 32). Stage W[a,:,:] (16KB) + B-tile (4KB) in LDS,
// hoist W column (32 floats, this thread's z) into registers, then 16
// outputs/thread as register FMAs with LDS-broadcast B reads.
__global__ __launch_bounds__(256) void tmat_kernel(
    const float* __restrict__ Bm, const float* __restrict__ w_out,
    float* __restrict__ T) {
  int a  = blockIdx.x;   // 0..31
  int jt = blockIdx.y;   // 0..15 -> j tile of 32
  int tid = threadIdx.x;
  __shared__ float Wl[CH * CZ];   // [b][z] 16 KB
  __shared__ float Bl[32 * CH];   // [jl][b] 4 KB

  const float4* Wg = (const float4*)(w_out + (size_t)a * CH * CZ);
  float4* Wl4 = (float4*)Wl;
  #pragma unroll
  for (int v = 0; v < 4; ++v) Wl4[tid + v * 256] = Wg[tid + v * 256];
  const float4* Bg = (const float4*)(Bm + (size_t)jt * 32 * CH);
  ((float4*)Bl)[tid & 255] = Bg[tid & 255];
  __syncthreads();

  int z = tid & (CZ - 1);
  int jh = tid >> 7;  // 0 or 1
  float wreg[CH];
  #pragma unroll
  for (int b = 0; b < CH; ++b) wreg[b] = Wl[b * CZ + z];

  #pragma unroll 4
  for (int jj = 0; jj < 16; ++jj) {
    int jl = jh * 16 + jj;
    float acc = 0.f;
    #pragma unroll
    for (int b = 0; b < CH; ++b) acc += Bl[jl * CH + b] * wreg[b];
    T[((size_t)(jt * 32 + jl) * CH + a) * CZ + z] = acc;
  }
}

// ---------------- Kernel 3: z[i,j,:] = A[i,:] @ T[j,:,:] + b_out ----------------
__global__ __launch_bounds__(256) void outer_kernel(
    const float* __restrict__ A, const float* __restrict__ T,
    const float* __restrict__ b_out, float* __restrict__ out) {
  int it = blockIdx.x;  // 0..7
  int j  = blockIdx.y;  // 0..511
  int tid = threadIdx.x;
  __shared__ float At[CH * 64];   // [a][il]  (transposed A tile)
  __shared__ float Tl[CH * CZ];   // [a][z]
  __shared__ float bo[CZ];

  if (tid < CZ) bo[tid] = b_out[tid];

  for (int idx = tid; idx < 64 * CH; idx += 256) {
    int il = idx >> 5, a = idx & 31;
    At[a * 64 + il] = A[(it * 64 + il) * CH + a];
  }
  const float4* Tg = (const float4*)(T + (size_t)j * CH * CZ);
  float4* Tl4 = (float4*)Tl;
  for (int v = tid; v < CH * CZ / 4; v += 256) Tl4[v] = Tg[v];
  __syncthreads();

  int tx = tid & 15, ty = tid >> 4;
  float acc[4][8];
  #pragma unroll
  for (int r = 0; r < 4; ++r)
    #pragma unroll
    for (int c = 0; c < 8; ++c) acc[r][c] = 0.f;

  #pragma unroll 8
  for (int a = 0; a < CH; ++a) {
    float4 av = *(const float4*)&At[a * 64 + ty * 4];
    float4 t0 = *(const float4*)&Tl[a * CZ + tx * 4];
    float4 t1 = *(const float4*)&Tl[a * CZ + 64 + tx * 4];
    const float avr[4] = {av.x, av.y, av.z, av.w};
    const float t0r[4] = {t0.x, t0.y, t0.z, t0.w};
    const float t1r[4] = {t1.x, t1.y, t1.z, t1.w};
    #pragma unroll
    for (int r = 0; r < 4; ++r) {
      #pragma unroll
      for (int c = 0; c < 4; ++c) {
        acc[r][c]     += avr[r] * t0r[c];
        acc[r][c + 4] += avr[r] * t1r[c];
      }
    }
  }

  float4 bv0 = *(const float4*)&bo[tx * 4];
  float4 bv1 = *(const float4*)&bo[64 + tx * 4];
  const float b0r[4] = {bv0.x, bv0.y, bv0.z, bv0.w};
  const float b1r[4] = {bv1.x, bv1.y, bv1.z, bv1.w};

  #pragma unroll
  for (int r = 0; r < 4; ++r) {
    int i = it * 64 + ty * 4 + r;
    float* op = out + ((size_t)i * LL + j) * CZ;
    float4 o0, o1;
    o0.x = acc[r][0] + b0r[0]; o0.y = acc[r][1] + b0r[1];
    o0.z = acc[r][2] + b0r[2]; o0.w = acc[r][3] + b0r[3];
    o1.x = acc[r][4] + b1r[0]; o1.y = acc[r][5] + b1r[1];
    o1.z = acc[r][6] + b1r[2]; o1.w = acc[r][7] + b1r[3];
    *(float4*)(op + tx * 4) = o0;
    *(float4*)(op + 64 + tx * 4) = o1;
  }
}

extern "C" void kernel_launch(void* const* d_in, const int* in_sizes, int n_in,
                              void* d_out, int out_size, void* d_ws, size_t ws_size,
                              hipStream_t stream) {
  const float* s     = (const float*)d_in[0];
  const float* gam   = (const float*)d_in[1];
  const float* bet   = (const float*)d_in[2];
  const float* w1    = (const float*)d_in[3];
  const float* b1    = (const float*)d_in[4];
  const float* w2    = (const float*)d_in[5];
  const float* b2    = (const float*)d_in[6];
  const float* w_out = (const float*)d_in[7];
  const float* b_out = (const float*)d_in[8];
  float* out = (float*)d_out;

  float* wsA = (float*)d_ws;            // 512*32 floats
  float* wsB = wsA + LL * CH;           // 512*32 floats
  float* wsT = wsB + LL * CH;           // 512*32*128 floats (8 MB)

  ln_proj_kernel<<<LL, 256, 0, stream>>>(s, gam, bet, w1, b1, w2, b2, wsA, wsB);
  tmat_kernel<<<dim3(CH, 16), 256, 0, stream>>>(wsB, w_out, wsT);
  outer_kernel<<<dim3(8, LL), 256, 0, stream>>>(wsA, wsT, b_out, out);
}

// Round 3
// 49.819 us; speedup vs baseline: 2.4372x; 1.4049x over previous
//
#include <hip/hip_runtime.h>

#define CS 384
#define CH 32
#define CZ 128
#define LL 512
#define EPSV 1e-5f

typedef __attribute__((ext_vector_type(8))) short bf16x8;
typedef __attribute__((ext_vector_type(4))) float f32x4;

static __device__ __forceinline__ unsigned short f2bf(float x) {
  union { float f; unsigned int u; } c; c.f = x;
  unsigned int r = c.u + 0x7FFFu + ((c.u >> 16) & 1u);  // RNE
  return (unsigned short)(r >> 16);
}

// ---------------- Kernel 1: LayerNorm + two projections ----------------
__global__ __launch_bounds__(256) void ln_proj_kernel(
    const float* __restrict__ s, const float* __restrict__ gamma,
    const float* __restrict__ beta,
    const float* __restrict__ w1, const float* __restrict__ b1,
    const float* __restrict__ w2, const float* __restrict__ b2,
    float* __restrict__ A, float* __restrict__ B) {
  int l = blockIdx.x;
  int tid = threadIdx.x;
  __shared__ float sn[CS];
  __shared__ float red[256];
  const float* srow = s + l * CS;

  float lsum = 0.f;
  for (int c = tid; c < CS; c += 256) { float x = srow[c]; sn[c] = x; lsum += x; }
  red[tid] = lsum; __syncthreads();
  for (int off = 128; off > 0; off >>= 1) {
    if (tid < off) red[tid] += red[tid + off];
    __syncthreads();
  }
  float mu = red[0] * (1.0f / CS);
  __syncthreads();

  float lvar = 0.f;
  for (int c = tid; c < CS; c += 256) { float d = sn[c] - mu; lvar += d * d; }
  red[tid] = lvar; __syncthreads();
  for (int off = 128; off > 0; off >>= 1) {
    if (tid < off) red[tid] += red[tid + off];
    __syncthreads();
  }
  float rstd = rsqrtf(red[0] * (1.0f / CS) + EPSV);
  __syncthreads();

  for (int c = tid; c < CS; c += 256)
    sn[c] = (sn[c] - mu) * rstd * gamma[c] + beta[c];
  __syncthreads();

  int o = tid >> 2, q = tid & 3;
  int h = o & 31;
  const float* w = (o < CH) ? w1 : w2;
  float acc = 0.f;
  int c0 = q * 96;
  #pragma unroll 8
  for (int c = c0; c < c0 + 96; ++c) acc += sn[c] * w[c * CH + h];
  red[tid] = acc; __syncthreads();
  if (q == 0) {
    float r = red[tid] + red[tid + 1] + red[tid + 2] + red[tid + 3];
    if (o < CH) A[l * CH + h] = r + b1[h];
    else        B[l * CH + h] = r + b2[h];
  }
}

// ---------------- Kernel 2: T[j,a,z] = sum_b B[j,b] * W[a,b,z] ----------------
// Grid (32 a, 32 jt of 16 j). W[a] (16KB) in LDS (conflict-free column reads),
// B-tile via float4 wave-broadcast reads. fp32 throughout.
__global__ __launch_bounds__(256) void tmat_kernel(
    const float* __restrict__ Bm, const float* __restrict__ w_out,
    float* __restrict__ T) {
  int a  = blockIdx.x;   // 0..31
  int jt = blockIdx.y;   // 0..31 -> 16 j
  int tid = threadIdx.x;
  __shared__ float Wl[CH * CZ];   // [b][z] 16 KB
  __shared__ float Bl[16 * CH];   // [jl][b] 2 KB

  const float4* Wg = (const float4*)(w_out + (size_t)a * CH * CZ);
  float4* Wl4 = (float4*)Wl;
  #pragma unroll
  for (int v = 0; v < 4; ++v) Wl4[tid + v * 256] = Wg[tid + v * 256];
  if (tid < 128) ((float4*)Bl)[tid] = ((const float4*)(Bm + (size_t)jt * 16 * CH))[tid];
  __syncthreads();

  int z = tid & (CZ - 1);
  int jh = tid >> 7;  // 0 or 1 -> 8 j's each
  float wreg[CH];
  #pragma unroll
  for (int b = 0; b < CH; ++b) wreg[b] = Wl[b * CZ + z];

  #pragma unroll
  for (int jj = 0; jj < 8; ++jj) {
    int jl = jh * 8 + jj;
    const float4* bj = (const float4*)&Bl[jl * CH];
    float acc = 0.f;
    #pragma unroll
    for (int v = 0; v < 8; ++v) {
      float4 bv = bj[v];
      acc += bv.x * wreg[v * 4 + 0] + bv.y * wreg[v * 4 + 1]
           + bv.z * wreg[v * 4 + 2] + bv.w * wreg[v * 4 + 3];
    }
    T[((size_t)(jt * 16 + jl) * CH + a) * CZ + z] = acc;
  }
}

// ---------------- Kernel 3 (MFMA): z[i,j,:] = A[i,:] @ T[j,:,:] + b_out -------
// Grid (4 i-tiles of 128, 512 j). 256 threads = 4 waves; wave w owns i rows
// [it*128 + w*32, +32) as two 16-row MFMA tiles. K=32=C_H in ONE
// mfma_f32_16x16x32_bf16 per (i-tile, z-tile). T_j staged to LDS transposed
// bf16 [z][a] (pad 40 shorts); A-frags straight from global (fp32->bf16).
#define TPAD 40
__global__ __launch_bounds__(256) void outer_mfma(
    const float* __restrict__ A, const float* __restrict__ T,
    const float* __restrict__ b_out, float* __restrict__ out) {
  int it = blockIdx.x;  // 0..3
  int j  = blockIdx.y;  // 0..511
  int tid = threadIdx.x;
  __shared__ __align__(16) unsigned short Tt[CZ][TPAD];  // [z][a] bf16

  // Stage T[j] (fp32 [32a][128z]) -> Tt[z][a] bf16.
  // Thread: z = tid&127, a-quad per pass; global reads coalesced (z across
  // lanes), LDS writes are one ds_write_b64 per quad.
  {
    const float* Tj = T + (size_t)j * CH * CZ;
    int z = tid & 127;
    int a0 = (tid >> 7) * 4;  // 0 or 4
    #pragma unroll
    for (int pass = 0; pass < 4; ++pass) {
      int ab = a0 + pass * 8;
      float v0 = Tj[(ab + 0) * CZ + z];
      float v1 = Tj[(ab + 1) * CZ + z];
      float v2 = Tj[(ab + 2) * CZ + z];
      float v3 = Tj[(ab + 3) * CZ + z];
      ushort4 pk;
      pk.x = f2bf(v0); pk.y = f2bf(v1); pk.z = f2bf(v2); pk.w = f2bf(v3);
      *(ushort4*)&Tt[z][ab] = pk;
    }
  }

  int w = tid >> 6;        // wave 0..3
  int l = tid & 63;        // lane
  int q = l >> 4;          // quarter 0..3
  int r = l & 15;          // row/col within tile

  // A-frags for the wave's two 16-row i-tiles: lane holds A[r][8q..8q+7].
  bf16x8 af[2];
  #pragma unroll
  for (int t2 = 0; t2 < 2; ++t2) {
    int irow = it * 128 + w * 32 + t2 * 16 + r;
    const float* Ar = A + (size_t)irow * CH + 8 * q;
    float4 x0 = *(const float4*)Ar;
    float4 x1 = *(const float4*)(Ar + 4);
    bf16x8 f;
    f[0] = (short)f2bf(x0.x); f[1] = (short)f2bf(x0.y);
    f[2] = (short)f2bf(x0.z); f[3] = (short)f2bf(x0.w);
    f[4] = (short)f2bf(x1.x); f[5] = (short)f2bf(x1.y);
    f[6] = (short)f2bf(x1.z); f[7] = (short)f2bf(x1.w);
    af[t2] = f;
  }

  // Bias per z-tile for this lane's column.
  float bo[8];
  #pragma unroll
  for (int zt = 0; zt < 8; ++zt) bo[zt] = b_out[zt * 16 + r];

  f32x4 acc[2][8];
  f32x4 zer = {0.f, 0.f, 0.f, 0.f};
  #pragma unroll
  for (int t2 = 0; t2 < 2; ++t2)
    #pragma unroll
    for (int zt = 0; zt < 8; ++zt) acc[t2][zt] = zer;

  __syncthreads();

  #pragma unroll
  for (int zt = 0; zt < 8; ++zt) {
    // B-frag: lane holds T[k=8q..8q+7][z = zt*16 + r] from Tt row.
    bf16x8 bf = *(const bf16x8*)&Tt[zt * 16 + r][8 * q];
    acc[0][zt] = __builtin_amdgcn_mfma_f32_16x16x32_bf16(af[0], bf, acc[0][zt], 0, 0, 0);
    acc[1][zt] = __builtin_amdgcn_mfma_f32_16x16x32_bf16(af[1], bf, acc[1][zt], 0, 0, 0);
  }

  // C/D layout: col = r, row = 4q + reg (m89-verified). Store + bias.
  #pragma unroll
  for (int t2 = 0; t2 < 2; ++t2) {
    int ibase = it * 128 + w * 32 + t2 * 16 + 4 * q;
    #pragma unroll
    for (int zt = 0; zt < 8; ++zt) {
      #pragma unroll
      for (int rg = 0; rg < 4; ++rg) {
        out[((size_t)(ibase + rg) * LL + j) * CZ + zt * 16 + r] =
            acc[t2][zt][rg] + bo[zt];
      }
    }
  }
}

extern "C" void kernel_launch(void* const* d_in, const int* in_sizes, int n_in,
                              void* d_out, int out_size, void* d_ws, size_t ws_size,
                              hipStream_t stream) {
  const float* s     = (const float*)d_in[0];
  const float* gam   = (const float*)d_in[1];
  const float* bet   = (const float*)d_in[2];
  const float* w1    = (const float*)d_in[3];
  const float* b1    = (const float*)d_in[4];
  const float* w2    = (const float*)d_in[5];
  const float* b2    = (const float*)d_in[6];
  const float* w_out = (const float*)d_in[7];
  const float* b_out = (const float*)d_in[8];
  float* out = (float*)d_out;

  float* wsA = (float*)d_ws;            // 512*32 floats
  float* wsB = wsA + LL * CH;           // 512*32 floats
  float* wsT = wsB + LL * CH;           // 512*32*128 floats (8 MB)

  ln_proj_kernel<<<LL, 256, 0, stream>>>(s, gam, bet, w1, b1, w2, b2, wsA, wsB);
  tmat_kernel<<<dim3(CH, 32), 256, 0, stream>>>(wsB, w_out, wsT);
  outer_mfma<<<dim3(4, LL), 256, 0, stream>>>(wsA, wsT, b_out, out);
}

// Round 4
// 49.233 us; speedup vs baseline: 2.4662x; 1.0119x over previous
//
#include <hip/hip_runtime.h>

#define CS 384
#define CH 32
#define CZ 128
#define LL 512
#define EPSV 1e-5f

typedef __attribute__((ext_vector_type(8))) short bf16x8;
typedef __attribute__((ext_vector_type(4))) float f32x4;

static __device__ __forceinline__ unsigned short f2bf(float x) {
  union { float f; unsigned int u; } c; c.f = x;
  unsigned int r = c.u + 0x7FFFu + ((c.u >> 16) & 1u);  // RNE
  return (unsigned short)(r >> 16);
}

// ---------------- Kernel 1: LayerNorm + two projections ----------------
// One block per l. Single-pass sum+sumsq shuffle reduction; projection with
// coalesced weight reads (lanes 0..31 -> w1 h=0..31, lanes 32..63 -> w2).
__global__ __launch_bounds__(256) void ln_proj_kernel(
    const float* __restrict__ s, const float* __restrict__ gamma,
    const float* __restrict__ beta,
    const float* __restrict__ w1, const float* __restrict__ b1,
    const float* __restrict__ w2, const float* __restrict__ b2,
    float* __restrict__ A, float* __restrict__ B) {
  int l = blockIdx.x;
  int tid = threadIdx.x;
  __shared__ float sn[CS];
  __shared__ float wred[8];
  __shared__ float red[256];
  const float* srow = s + l * CS;

  float lsum = 0.f, lsq = 0.f;
  for (int c = tid; c < CS; c += 256) {
    float x = srow[c]; sn[c] = x; lsum += x; lsq += x * x;
  }
  #pragma unroll
  for (int off = 32; off > 0; off >>= 1) {
    lsum += __shfl_down(lsum, off);
    lsq  += __shfl_down(lsq, off);
  }
  int wv = tid >> 6;
  if ((tid & 63) == 0) { wred[wv] = lsum; wred[4 + wv] = lsq; }
  __syncthreads();
  float s1 = wred[0] + wred[1] + wred[2] + wred[3];
  float s2 = wred[4] + wred[5] + wred[6] + wred[7];
  float mu = s1 * (1.0f / CS);
  float var = s2 * (1.0f / CS) - mu * mu;
  float rstd = rsqrtf(var + EPSV);

  for (int c = tid; c < CS; c += 256)
    sn[c] = (sn[c] - mu) * rstd * gamma[c] + beta[c];
  __syncthreads();

  // 64 outputs (h<32: A via w1, else B via w2), 4 c-chunks of 96.
  int o = tid & 63, q = tid >> 6;
  int h = o & 31;
  const float* w = (o < CH) ? w1 : w2;
  float acc = 0.f;
  int c0 = q * 96;
  #pragma unroll 8
  for (int c = c0; c < c0 + 96; ++c) acc += sn[c] * w[c * CH + h];
  red[tid] = acc; __syncthreads();
  if (tid < 64) {
    float r = red[tid] + red[tid + 64] + red[tid + 128] + red[tid + 192];
    if (o < CH) A[l * CH + h] = r + b1[h];
    else        B[l * CH + h] = r + b2[h];
  }
}

// ---------------- Kernel 2: T[j,a,z] = sum_b B[j,b] * W[a,b,z] ----------------
__global__ __launch_bounds__(256) void tmat_kernel(
    const float* __restrict__ Bm, const float* __restrict__ w_out,
    float* __restrict__ T) {
  int a  = blockIdx.x;   // 0..31
  int jt = blockIdx.y;   // 0..31 -> 16 j
  int tid = threadIdx.x;
  __shared__ float Wl[CH * CZ];   // [b][z] 16 KB
  __shared__ float Bl[16 * CH];   // [jl][b] 2 KB

  const float4* Wg = (const float4*)(w_out + (size_t)a * CH * CZ);
  float4* Wl4 = (float4*)Wl;
  #pragma unroll
  for (int v = 0; v < 4; ++v) Wl4[tid + v * 256] = Wg[tid + v * 256];
  if (tid < 128) ((float4*)Bl)[tid] = ((const float4*)(Bm + (size_t)jt * 16 * CH))[tid];
  __syncthreads();

  int z = tid & (CZ - 1);
  int jh = tid >> 7;  // 0 or 1 -> 8 j's each
  float wreg[CH];
  #pragma unroll
  for (int b = 0; b < CH; ++b) wreg[b] = Wl[b * CZ + z];

  #pragma unroll
  for (int jj = 0; jj < 8; ++jj) {
    int jl = jh * 8 + jj;
    const float4* bj = (const float4*)&Bl[jl * CH];
    float acc = 0.f;
    #pragma unroll
    for (int v = 0; v < 8; ++v) {
      float4 bv = bj[v];
      acc += bv.x * wreg[v * 4 + 0] + bv.y * wreg[v * 4 + 1]
           + bv.z * wreg[v * 4 + 2] + bv.w * wreg[v * 4 + 3];
    }
    T[((size_t)(jt * 16 + jl) * CH + a) * CZ + z] = acc;
  }
}

// ---------------- Kernel 3 (MFMA, swapped operands): ----------------
// D = T^T (z x a) . A_i (a x i): A-operand frag = Tt[z=r][a=8q..8q+7] (the
// same LDS read as before), B-operand frag = A[i=r][a=8q..8q+7] (same global
// load as before). D layout: row=4q+reg -> z (CONSECUTIVE), col=r -> i, so
// each lane stores float4 of contiguous z. 16 float4 stores/thread vs 64
// scalar dwords.
#define TPAD 40
__global__ __launch_bounds__(256) void outer_mfma(
    const float* __restrict__ A, const float* __restrict__ T,
    const float* __restrict__ b_out, float* __restrict__ out) {
  int it = blockIdx.x;  // 0..3
  int j  = blockIdx.y;  // 0..511
  int tid = threadIdx.x;
  __shared__ __align__(16) unsigned short Tt[CZ][TPAD];  // [z][a] bf16

  // Stage T[j] (fp32 [32a][128z]) -> Tt[z][a] bf16; global reads coalesced.
  {
    const float* Tj = T + (size_t)j * CH * CZ;
    int z = tid & 127;
    int a0 = (tid >> 7) * 4;  // 0 or 4
    #pragma unroll
    for (int pass = 0; pass < 4; ++pass) {
      int ab = a0 + pass * 8;
      float v0 = Tj[(ab + 0) * CZ + z];
      float v1 = Tj[(ab + 1) * CZ + z];
      float v2 = Tj[(ab + 2) * CZ + z];
      float v3 = Tj[(ab + 3) * CZ + z];
      ushort4 pk;
      pk.x = f2bf(v0); pk.y = f2bf(v1); pk.z = f2bf(v2); pk.w = f2bf(v3);
      *(ushort4*)&Tt[z][ab] = pk;
    }
  }

  int w = tid >> 6;        // wave 0..3
  int l = tid & 63;        // lane
  int q = l >> 4;          // quarter 0..3
  int r = l & 15;          // row/col within tile

  // B-operand frags: lane holds A[i = r][a = 8q..8q+7] for two 16-row i-tiles.
  bf16x8 af[2];
  #pragma unroll
  for (int t2 = 0; t2 < 2; ++t2) {
    int irow = it * 128 + w * 32 + t2 * 16 + r;
    const float* Ar = A + (size_t)irow * CH + 8 * q;
    float4 x0 = *(const float4*)Ar;
    float4 x1 = *(const float4*)(Ar + 4);
    bf16x8 f;
    f[0] = (short)f2bf(x0.x); f[1] = (short)f2bf(x0.y);
    f[2] = (short)f2bf(x0.z); f[3] = (short)f2bf(x0.w);
    f[4] = (short)f2bf(x1.x); f[5] = (short)f2bf(x1.y);
    f[6] = (short)f2bf(x1.z); f[7] = (short)f2bf(x1.w);
    af[t2] = f;
  }

  f32x4 acc[2][8];
  f32x4 zer = {0.f, 0.f, 0.f, 0.f};
  #pragma unroll
  for (int t2 = 0; t2 < 2; ++t2)
    #pragma unroll
    for (int zt = 0; zt < 8; ++zt) acc[t2][zt] = zer;

  __syncthreads();

  #pragma unroll
  for (int zt = 0; zt < 8; ++zt) {
    // A-operand frag: lane holds T^T[z = zt*16 + r][a = 8q..8q+7].
    bf16x8 bf = *(const bf16x8*)&Tt[zt * 16 + r][8 * q];
    acc[0][zt] = __builtin_amdgcn_mfma_f32_16x16x32_bf16(bf, af[0], acc[0][zt], 0, 0, 0);
    acc[1][zt] = __builtin_amdgcn_mfma_f32_16x16x32_bf16(bf, af[1], acc[1][zt], 0, 0, 0);
  }

  // Bias per z-quad (4 consecutive z for this lane).
  f32x4 bo4[8];
  #pragma unroll
  for (int zt = 0; zt < 8; ++zt)
    bo4[zt] = *(const f32x4*)&b_out[zt * 16 + 4 * q];

  // D: row = 4q + reg -> z, col = r -> i. One float4 store per (t2, zt).
  #pragma unroll
  for (int t2 = 0; t2 < 2; ++t2) {
    int i = it * 128 + w * 32 + t2 * 16 + r;
    float* op = out + ((size_t)i * LL + j) * CZ + 4 * q;
    #pragma unroll
    for (int zt = 0; zt < 8; ++zt) {
      f32x4 v = acc[t2][zt] + bo4[zt];
      *(f32x4*)(op + zt * 16) = v;
    }
  }
}

extern "C" void kernel_launch(void* const* d_in, const int* in_sizes, int n_in,
                              void* d_out, int out_size, void* d_ws, size_t ws_size,
                              hipStream_t stream) {
  const float* s     = (const float*)d_in[0];
  const float* gam   = (const float*)d_in[1];
  const float* bet   = (const float*)d_in[2];
  const float* w1    = (const float*)d_in[3];
  const float* b1    = (const float*)d_in[4];
  const float* w2    = (const float*)d_in[5];
  const float* b2    = (const float*)d_in[6];
  const float* w_out = (const float*)d_in[7];
  const float* b_out = (const float*)d_in[8];
  float* out = (float*)d_out;

  float* wsA = (float*)d_ws;            // 512*32 floats
  float* wsB = wsA + LL * CH;           // 512*32 floats
  float* wsT = wsB + LL * CH;           // 512*32*128 floats (8 MB)

  ln_proj_kernel<<<LL, 256, 0, stream>>>(s, gam, bet, w1, b1, w2, b2, wsA, wsB);
  tmat_kernel<<<dim3(CH, 32), 256, 0, stream>>>(wsB, w_out, wsT);
  outer_mfma<<<dim3(4, LL), 256, 0, stream>>>(wsA, wsT, b_out, out);
}